// Round 8
// baseline (62.545 us; speedup 1.0000x reference)
//
#include <hip/hip_runtime.h>

// Problem constants (must match reference)
#define L_SZ 100000
#define K_DIM 128
#define B_SZ 16384
#define CS_SZ 8
#define NS_SZ 20
#define NEPOCH 10
#define LOG_SQRT_2PI 0.9189385332046727
#define NBLOCKS 4096

typedef float f32x4 __attribute__((ext_vector_type(4)));

// softplus(x) = max(x,0) + log(1 + exp(-|x|)); fast-math variant is fine:
// tolerance is ~2% relative on a ~2.6e7 loss.
__device__ __forceinline__ float softplus_f(float x) {
    return fmaxf(x, 0.0f) + __logf(1.0f + __expf(-fabsf(x)));
}

// ---- fused likelihood + prior kernel ---------------------------------------
// 4096 blocks x 256 threads (4 waves); one batch element per wave.
// KEY CHANGE (R7): __launch_bounds__(256,4) raises the VGPR cap so ALL 28
// gather loads (12 target half-rows + 16 ctx half-rows) are issued
// unconditionally into registers before any consumption. R6's VGPR_Count=32
// showed the compiler was serializing gather iterations on miss latency
// (1-2 loads in flight per wave); this trades occupancy for memory ILP.
// Lane (g, j): group g in 0..3, j in 0..15. Half-row split: lane j holds dims
// 4j..4j+3 and 64+4j..64+4j+3 -> each 64B line of a row touched exactly once.
// Group g owns targets n = 4s+g (n=0 positive); invalid slots (n>=21) load
// row 0 harmlessly and are masked at the softplus.
__global__ __launch_bounds__(256, 4) void fused_kernel(
    const int* __restrict__ contexts, const int* __restrict__ targets,
    const int* __restrict__ neg_idx, const float* __restrict__ tW,
    const float* __restrict__ cW,
    double* __restrict__ pll, double* __restrict__ pprior)
{
    const int lane = threadIdx.x & 63;
    const int wave = threadIdx.x >> 6;
    const int j = lane & 15;      // position within 16-lane group
    const int g = lane >> 4;      // group 0..3

    const int n_mine = 4 * j + g;           // target this lane softpluses
    const bool valid = (n_mine < 21);
    const float sgn = (n_mine == 0) ? -1.0f : 1.0f;  // pos: softplus(-eta)

    // wave-uniform batch index -> SGPR so uniform index loads become s_load
    const int b = __builtin_amdgcn_readfirstlane(blockIdx.x * 4 + wave);

    // ---- resolve indices (tiny loads) --------------------------------------
    int ctxi[CS_SZ];
    #pragma unroll
    for (int c = 0; c < CS_SZ; ++c) ctxi[c] = contexts[b * CS_SZ + c];

    int tidx[6];
    #pragma unroll
    for (int s = 0; s < 6; ++s) {
        const int n = 4 * s + g;
        int t = 0;                               // clamped for invalid slots
        if (n == 0)       t = targets[b];
        else if (n < 21)  t = neg_idx[b * NS_SZ + (n - 1)];
        tidx[s] = t;
    }

    // ---- issue ALL gather loads up front (28 independent 16B loads) --------
    float4 t0[6], t1[6];
    #pragma unroll
    for (int s = 0; s < 6; ++s) {
        const float* base = &tW[(size_t)tidx[s] * K_DIM];
        t0[s] = *reinterpret_cast<const float4*>(base + 4 * j);
        t1[s] = *reinterpret_cast<const float4*>(base + 64 + 4 * j);
    }
    float4 c0[CS_SZ], c1[CS_SZ];
    #pragma unroll
    for (int c = 0; c < CS_SZ; ++c) {
        const float* base = &cW[(size_t)ctxi[c] * K_DIM];
        c0[c] = *reinterpret_cast<const float4*>(base + 4 * j);
        c1[c] = *reinterpret_cast<const float4*>(base + 64 + 4 * j);
    }

    // ---- ctx_sum accumulate -------------------------------------------------
    float4 s0 = {0.f, 0.f, 0.f, 0.f}, s1 = {0.f, 0.f, 0.f, 0.f};
    #pragma unroll
    for (int c = 0; c < CS_SZ; ++c) {
        s0.x += c0[c].x; s0.y += c0[c].y; s0.z += c0[c].z; s0.w += c0[c].w;
        s1.x += c1[c].x; s1.y += c1[c].y; s1.z += c1[c].z; s1.w += c1[c].w;
    }

    // ---- 6 dots first (ILP), then 6 independent butterfly chains -----------
    float p[6];
    #pragma unroll
    for (int s = 0; s < 6; ++s) {
        p[s] = t0[s].x * s0.x + t0[s].y * s0.y + t0[s].z * s0.z + t0[s].w * s0.w
             + t1[s].x * s1.x + t1[s].y * s1.y + t1[s].z * s1.z + t1[s].w * s1.w;
    }
    #pragma unroll
    for (int o = 1; o <= 8; o <<= 1) {
        #pragma unroll
        for (int s = 0; s < 6; ++s) p[s] += __shfl_xor(p[s], o, 16);
    }
    float keep = 0.0f;
    #pragma unroll
    for (int s = 0; s < 6; ++s) keep = (j == s) ? p[s] : keep;
    float lacc = valid ? softplus_f(sgn * keep) : 0.0f;

    // ---- prior sweep: grid-stride sum of squares over both tables ----------
    const int NT4 = (L_SZ * K_DIM) / 4;          // 3,200,000
    const int NC4 = ((L_SZ + 1) * K_DIM) / 4;    // 3,200,032
    const int tid = blockIdx.x * blockDim.x + threadIdx.x;
    const int stride = gridDim.x * blockDim.x;

    float pacc = 0.0f;
    const f32x4* t4 = reinterpret_cast<const f32x4*>(tW);
    for (int i = tid; i < NT4; i += stride) {
        const f32x4 v = t4[i];
        pacc += v.x * v.x + v.y * v.y + v.z * v.z + v.w * v.w;
    }
    const f32x4* c4 = reinterpret_cast<const f32x4*>(cW);
    for (int i = tid; i < NC4; i += stride) {
        const f32x4 v = c4[i];
        pacc += v.x * v.x + v.y * v.y + v.z * v.z + v.w * v.w;
    }

    // ---- per-wave then per-block reduction ---------------------------------
    #pragma unroll
    for (int o = 32; o; o >>= 1) {
        lacc += __shfl_xor(lacc, o, 64);
        pacc += __shfl_xor(pacc, o, 64);
    }
    __shared__ float sl[4], sp[4];
    if (lane == 0) { sl[wave] = lacc; sp[wave] = pacc; }
    __syncthreads();
    if (threadIdx.x == 0) {
        pll[blockIdx.x]    = (double)(sl[0] + sl[1] + sl[2] + sl[3]);
        pprior[blockIdx.x] = (double)(sp[0] + sp[1] + sp[2] + sp[3]);
    }
}

// ---- finalize: reduce partials, assemble scalar loss ------------------------
__global__ __launch_bounds__(256) void finalize_kernel(
    const double* __restrict__ pll, int nll,
    const double* __restrict__ pprior, int nprior,
    float* __restrict__ out)
{
    double a = 0.0, p = 0.0;
    for (int i = threadIdx.x; i < nll; i += 256) a += pll[i];
    for (int i = threadIdx.x; i < nprior; i += 256) p += pprior[i];

    __shared__ double sA[256], sP[256];
    sA[threadIdx.x] = a; sP[threadIdx.x] = p;
    __syncthreads();
    for (int s = 128; s > 0; s >>= 1) {
        if (threadIdx.x < s) {
            sA[threadIdx.x] += sA[threadIdx.x + s];
            sP[threadIdx.x] += sP[threadIdx.x + s];
        }
        __syncthreads();
    }
    if (threadIdx.x == 0) {
        // loss = NEPOCH*sum(softplus) + 0.5*sum(x^2) + count*LOG_SQRT_2PI
        const double C = (double)((2LL * L_SZ + 1) * K_DIM) * LOG_SQRT_2PI;
        const double loss = (double)NEPOCH * sA[0] + 0.5 * sP[0] + C;
        out[0] = (float)loss;
    }
}

extern "C" void kernel_launch(void* const* d_in, const int* in_sizes, int n_in,
                              void* d_out, int out_size, void* d_ws, size_t ws_size,
                              hipStream_t stream) {
    const int*   contexts = (const int*)d_in[0];
    const int*   targets  = (const int*)d_in[1];
    const int*   neg_idx  = (const int*)d_in[2];
    const float* tW       = (const float*)d_in[3];
    const float* cW       = (const float*)d_in[4];
    float* out = (float*)d_out;

    double* pll    = (double*)d_ws;          // NBLOCKS doubles
    double* pprior = pll + NBLOCKS;          // NBLOCKS doubles

    fused_kernel<<<NBLOCKS, 256, 0, stream>>>(contexts, targets, neg_idx,
                                              tW, cW, pll, pprior);
    finalize_kernel<<<1, 256, 0, stream>>>(pll, NBLOCKS, pprior, NBLOCKS, out);
}